// Round 1
// baseline (168.434 us; speedup 1.0000x reference)
//
#include <hip/hip_runtime.h>
#include <math.h>

#define M_CB 8
#define K_CB 1024
#define D_CB 128
#define HW   1024
#define NB   4
#define NPIX 64
#define KT   64
#define HALF_LOG_2PI 0.9189385332046727f
#define EPS_S 1e-5f

// ---------------- kernel 1: logsumexp of log_py_raw per codebook ----------------
__global__ __launch_bounds__(256) void vq_pre(const float* __restrict__ logpy,
                                              float* __restrict__ lse)
{
    const int m = blockIdx.x, tid = threadIdx.x;
    float4 v = reinterpret_cast<const float4*>(logpy + (size_t)m * K_CB)[tid];
    float mx = fmaxf(fmaxf(v.x, v.y), fmaxf(v.z, v.w));
    #pragma unroll
    for (int o = 32; o >= 1; o >>= 1) mx = fmaxf(mx, __shfl_xor(mx, o, 64));
    __shared__ float wmax[4];
    __shared__ float wsum[4];
    if ((tid & 63) == 0) wmax[tid >> 6] = mx;
    __syncthreads();
    mx = fmaxf(fmaxf(wmax[0], wmax[1]), fmaxf(wmax[2], wmax[3]));
    float e = expf(v.x - mx) + expf(v.y - mx) + expf(v.z - mx) + expf(v.w - mx);
    #pragma unroll
    for (int o = 32; o >= 1; o >>= 1) e += __shfl_xor(e, o, 64);
    if ((tid & 63) == 0) wsum[tid >> 6] = e;
    __syncthreads();
    if (tid == 0) lse[m] = mx + logf(wsum[0] + wsum[1] + wsum[2] + wsum[3]);
}

// ---------------- kernel 2: fused dist + online softmax/KL/argmax + sample ------
__global__ __launch_bounds__(256, 2) void vq_main(
    const float* __restrict__ x, const float* __restrict__ mus,
    const float* __restrict__ scales, const float* __restrict__ logpy,
    const float* __restrict__ lse, float* __restrict__ out,
    float* __restrict__ partial)
{
    __shared__ float xT[D_CB][NPIX];   // 32 KB: xT[d][p]
    __shared__ float muT[D_CB][KT];    // 32 KB: muT[d][kk]  (aliased for merge states later)

    const int tid = threadIdx.x;
    const int bx  = blockIdx.x;        // 0..63 pixel tile
    const int m   = blockIdx.y;        // 0..7  codebook
    const int bimg = bx >> 4;          // image 0..3
    const int hw0  = (bx & 15) * NPIX; // pixel offset within image
    const size_t xbase = (size_t)bimg * (M_CB * D_CB * HW) + (size_t)m * D_CB * HW + hw0;

    const int ti = tid >> 4;           // k microtile group 0..15
    const int tj = tid & 15;           // pixel microtile group 0..15
    const float lsem = lse[m];

    // ---- stage x tile (coalesced: consecutive lanes -> consecutive pixels) ----
    {
        const int p = tid & 63, d0 = tid >> 6;
        for (int dd = d0; dd < D_CB; dd += 4)
            xT[dd][p] = x[xbase + (size_t)dd * HW + p];
    }
    __syncthreads();

    // ---- per-thread x_sq for its 4 pixels ----
    float xsql[4];
    #pragma unroll
    for (int j = 0; j < 4; ++j) {
        const int p = tj * 4 + j;
        float s = 0.f;
        #pragma unroll 8
        for (int dd = 0; dd < D_CB; ++dd) { const float v = xT[dd][p]; s = fmaf(v, v, s); }
        xsql[j] = s;
    }

    // ---- online softmax/KL state per pixel (4 pixels, over this thread's k's) ----
    float Mst[4], Sst[4], Ust[4], Vst[4];
    int Ist[4];
    #pragma unroll
    for (int j = 0; j < 4; ++j) { Mst[j] = -1e30f; Sst[j] = 0.f; Ust[j] = 0.f; Vst[j] = 0.f; Ist[j] = 0; }

    for (int kc = 0; kc < K_CB; kc += KT) {
        __syncthreads();   // previous epilogue done with muT before restage

        // ---- stage mu chunk transposed + per-k squared norm ----
        const int kk = tid >> 2, dg = tid & 3;
        const float* murow = mus + ((size_t)m * K_CB + kc + kk) * D_CB;
        float ssq = 0.f;
        #pragma unroll
        for (int j = 0; j < 8; ++j) {
            const int dd = dg * 4 + j * 16;
            const float4 v = *reinterpret_cast<const float4*>(murow + dd);
            muT[dd + 0][kk] = v.x; muT[dd + 1][kk] = v.y;
            muT[dd + 2][kk] = v.z; muT[dd + 3][kk] = v.w;
            ssq = fmaf(v.x, v.x, fmaf(v.y, v.y, fmaf(v.z, v.z, fmaf(v.w, v.w, ssq))));
        }
        ssq += __shfl_xor(ssq, 1, 64);
        ssq += __shfl_xor(ssq, 2, 64);   // all 4 dg lanes hold musq for kk
        __syncthreads();

        // ---- 4k x 4p register microtile over d ----
        float acc[4][4];
        #pragma unroll
        for (int u = 0; u < 4; ++u)
            #pragma unroll
            for (int j = 0; j < 4; ++j) acc[u][j] = 0.f;

        #pragma unroll 8
        for (int dd = 0; dd < D_CB; ++dd) {
            const float4 av = *reinterpret_cast<const float4*>(&muT[dd][ti * 4]);
            const float4 bv = *reinterpret_cast<const float4*>(&xT[dd][tj * 4]);
            const float a[4] = {av.x, av.y, av.z, av.w};
            const float b[4] = {bv.x, bv.y, bv.z, bv.w};
            #pragma unroll
            for (int u = 0; u < 4; ++u)
                #pragma unroll
                for (int j = 0; j < 4; ++j)
                    acc[u][j] = fmaf(a[u], b[j], acc[u][j]);
        }

        // ---- epilogue: logits + online update ----
        #pragma unroll
        for (int u = 0; u < 4; ++u) {
            const int k = kc + ti * 4 + u;
            const float musq_k = __shfl(ssq, ((ti & 3) << 4) + (u << 2), 64);
            const float sval = fmaxf(scales[m * K_CB + k], EPS_S);
            const float A = 0.5f / (sval * sval);
            const float lpy = logpy[m * K_CB + k];
            const float cons = fmaf(-(float)D_CB, logf(sval) + HALF_LOG_2PI, lpy) - A * musq_k;
            const float lp = lpy - lsem;
            #pragma unroll
            for (int j = 0; j < 4; ++j) {
                const float L = fmaf(2.f * A, acc[u][j], fmaf(-A, xsql[j], cons));
                const float diff = L - Mst[j];
                if (diff > 0.f) {
                    const float sc = __expf(-diff);
                    Ust[j] = (Ust[j] - diff * Sst[j]) * sc;
                    Sst[j] = fmaf(Sst[j], sc, 1.f);
                    Vst[j] = fmaf(Vst[j], sc, lp);
                    Mst[j] = L; Ist[j] = k;
                } else {
                    const float e = __expf(diff);
                    Sst[j] += e;
                    Ust[j] = fmaf(e, diff, Ust[j]);
                    Vst[j] = fmaf(e, lp, Vst[j]);
                }
            }
        }
    }

    // ---- merge 16 partial states per pixel (alias muT as scratch) ----
    __syncthreads();
    float* sb  = &muT[0][0];
    float* stM = sb;            float* stS = sb + 1024;
    float* stU = sb + 2048;     float* stV = sb + 3072;
    int*   stI = (int*)(sb + 4096);
    int*   sidx = (int*)(sb + 5120);

    #pragma unroll
    for (int j = 0; j < 4; ++j) {
        const int p = tj * 4 + j;
        stM[ti * 64 + p] = Mst[j];
        stS[ti * 64 + p] = Sst[j];
        stU[ti * 64 + p] = Ust[j];
        stV[ti * 64 + p] = Vst[j];
        stI[ti * 64 + p] = Ist[j];
    }
    __syncthreads();

    if (tid < 64) {
        float Ma = stM[tid], Sa = stS[tid], Ua = stU[tid], Va = stV[tid];
        int Ia = stI[tid];
        for (int t = 1; t < 16; ++t) {
            float Mb = stM[t * 64 + tid], Sb = stS[t * 64 + tid];
            float Ub = stU[t * 64 + tid], Vb = stV[t * 64 + tid];
            int Ib = stI[t * 64 + tid];
            const bool takeB = (Mb > Ma) || (Mb == Ma && Ib < Ia);
            if (takeB) {
                float tf;
                tf = Ma; Ma = Mb; Mb = tf;
                tf = Sa; Sa = Sb; Sb = tf;
                tf = Ua; Ua = Ub; Ub = tf;
                tf = Va; Va = Vb; Vb = tf;
                const int tI = Ia; Ia = Ib; Ib = tI;
            }
            const float dm = Mb - Ma;          // <= 0
            const float sc = __expf(dm);
            Sa = fmaf(Sb, sc, Sa);
            Ua = fmaf(fmaf(dm, Sb, Ub), sc, Ua);
            Va = fmaf(Vb, sc, Va);
        }
        float kl = (Ua - Va) / Sa - logf(Sa);
        sidx[tid] = Ia;
        #pragma unroll
        for (int o = 32; o >= 1; o >>= 1) kl += __shfl_xor(kl, o, 64);
        if (tid == 0) partial[blockIdx.y * 64 + bx] = kl;
    }
    __syncthreads();

    // ---- write sample: out[b, m*128+dd, hw0+p] = mus[m][idx[p]][dd] ----
    {
        const int p = tid & 63, d0 = tid >> 6;
        const int kidx = sidx[p];
        const float* mrow = mus + ((size_t)m * K_CB + kidx) * D_CB;
        for (int dd = d0; dd < D_CB; dd += 4)
            out[xbase + (size_t)dd * HW + p] = mrow[dd];
    }
}

// ---------------- kernel 3: reduce 512 partials -> kldesum, write scalars -------
__global__ __launch_bounds__(256) void vq_final(const float* __restrict__ partial,
                                                float* __restrict__ out)
{
    __shared__ float wred[4];
    const int tid = threadIdx.x;
    float v = partial[tid] + partial[tid + 256];
    #pragma unroll
    for (int o = 32; o >= 1; o >>= 1) v += __shfl_xor(v, o, 64);
    if ((tid & 63) == 0) wred[tid >> 6] = v;
    __syncthreads();
    if (tid == 0) {
        out[(size_t)NB * M_CB * D_CB * HW]     = (wred[0] + wred[1] + wred[2] + wred[3]) * 0.25f;
        out[(size_t)NB * M_CB * D_CB * HW + 1] = 0.f;
    }
}

extern "C" void kernel_launch(void* const* d_in, const int* in_sizes, int n_in,
                              void* d_out, int out_size, void* d_ws, size_t ws_size,
                              hipStream_t stream)
{
    const float* x      = (const float*)d_in[0];
    const float* mus    = (const float*)d_in[1];
    const float* scales = (const float*)d_in[2];
    const float* logpy  = (const float*)d_in[3];
    float* out = (float*)d_out;
    float* ws  = (float*)d_ws;
    float* partial = ws;        // 512 floats (per-block KL partials)
    float* lse     = ws + 512;  // 8 floats  (logsumexp of log_py_raw per m)

    vq_pre  <<<8,            256, 0, stream>>>(logpy, lse);
    vq_main <<<dim3(64, 8),  256, 0, stream>>>(x, mus, scales, logpy, lse, out, partial);
    vq_final<<<1,            256, 0, stream>>>(partial, out);
}

// Round 2
// 53.994 us; speedup vs baseline: 3.1195x; 3.1195x over previous
//
#include <hip/hip_runtime.h>
#include <math.h>

#define M_CB 8
#define K_CB 1024
#define D_CB 128
#define HW   1024
#define NB   4
#define HALF_LOG_2PI 0.9189385332046727f
#define EPS_S 1e-5f

typedef float f32x4 __attribute__((ext_vector_type(4)));
typedef short s16x8 __attribute__((ext_vector_type(8)));

__device__ __forceinline__ void gl2lds16(const void* g, void* l) {
    __builtin_amdgcn_global_load_lds(
        (const __attribute__((address_space(1))) void*)g,
        (__attribute__((address_space(3))) void*)l, 16, 0, 0);
}

__device__ __forceinline__ short f2bf(float f) {   // RNE fp32 -> bf16 bits
    unsigned u = __builtin_bit_cast(unsigned, f);
    u += 0x7fffu + ((u >> 16) & 1u);
    return (short)(u >> 16);
}

// ws layout (floats): lse @0 (8) | partial @16 (512) | A @1024 | c0 @3072*? see below
// A @1024 (8192), c0 @9216 (8192), lp @17408 (8192), mu bf16 @ float-offset 25600 (2MB)
#define WS_LSE   0
#define WS_PART  16
#define WS_A     1024
#define WS_C0    (WS_A + 8192)
#define WS_LP    (WS_C0 + 8192)
#define WS_MU_F  (WS_LP + 8192)   // cast to ushort* from here

// ---------------- kernel 1: logsumexp of log_py_raw per codebook ----------------
__global__ __launch_bounds__(256) void vq_pre(const float* __restrict__ logpy,
                                              float* __restrict__ lse)
{
    const int m = blockIdx.x, tid = threadIdx.x;
    float4 v = reinterpret_cast<const float4*>(logpy + (size_t)m * K_CB)[tid];
    float mx = fmaxf(fmaxf(v.x, v.y), fmaxf(v.z, v.w));
    #pragma unroll
    for (int o = 32; o >= 1; o >>= 1) mx = fmaxf(mx, __shfl_xor(mx, o, 64));
    __shared__ float wmax[4];
    __shared__ float wsum[4];
    if ((tid & 63) == 0) wmax[tid >> 6] = mx;
    __syncthreads();
    mx = fmaxf(fmaxf(wmax[0], wmax[1]), fmaxf(wmax[2], wmax[3]));
    float e = expf(v.x - mx) + expf(v.y - mx) + expf(v.z - mx) + expf(v.w - mx);
    #pragma unroll
    for (int o = 32; o >= 1; o >>= 1) e += __shfl_xor(e, o, 64);
    if ((tid & 63) == 0) wsum[tid >> 6] = e;
    __syncthreads();
    if (tid == 0) lse[m] = mx + logf(wsum[0] + wsum[1] + wsum[2] + wsum[3]);
}

// ------------- kernel 2: mus -> bf16 (swizzled) + per-k constants ----------------
// thread t handles one 16B dest block: db = t&15, k = (t>>4)&1023, m = t>>14
__global__ __launch_bounds__(256) void vq_convert(
    const float* __restrict__ mus, const float* __restrict__ scales,
    const float* __restrict__ logpy, const float* __restrict__ lse,
    ushort* __restrict__ wmu, float* __restrict__ Aarr,
    float* __restrict__ c0arr, float* __restrict__ lparr)
{
    const int t  = blockIdx.x * 256 + threadIdx.x;
    const int db = t & 15;
    const int k  = (t >> 4) & (K_CB - 1);
    const int m  = t >> 14;
    const float* row = mus + ((size_t)m * K_CB + k) * D_CB;
    const int d0 = 8 * (db ^ (k & 7));          // source d-block (swizzle involution)
    const float4 v0 = *reinterpret_cast<const float4*>(row + d0);
    const float4 v1 = *reinterpret_cast<const float4*>(row + d0 + 4);
    s16x8 o;
    o[0] = f2bf(v0.x); o[1] = f2bf(v0.y); o[2] = f2bf(v0.z); o[3] = f2bf(v0.w);
    o[4] = f2bf(v1.x); o[5] = f2bf(v1.y); o[6] = f2bf(v1.z); o[7] = f2bf(v1.w);
    *reinterpret_cast<s16x8*>(wmu + ((size_t)(m * K_CB + k) * D_CB + db * 8)) = o;

    float ssq = v0.x*v0.x + v0.y*v0.y + v0.z*v0.z + v0.w*v0.w
              + v1.x*v1.x + v1.y*v1.y + v1.z*v1.z + v1.w*v1.w;
    #pragma unroll
    for (int o2 = 8; o2 >= 1; o2 >>= 1) ssq += __shfl_xor(ssq, o2, 64);
    if (db == 0) {
        const float s = fmaxf(scales[m * K_CB + k], EPS_S);
        const float A = 0.5f / (s * s);
        const float lpy = logpy[m * K_CB + k];
        Aarr [m * K_CB + k] = A;
        c0arr[m * K_CB + k] = fmaf(-(float)D_CB, logf(s) + HALF_LOG_2PI, lpy) - A * ssq;
        lparr[m * K_CB + k] = lpy - lse[m];
    }
}

// ---------------- kernel 3: fused MFMA dist + online softmax/KL/argmax ----------
// LDS arena: [0,32K) xT fp32 [128][64]  -> later mu dbuf 2x16KB
//            [32K,36K) A_s  [36K,40K) c0_s  [40K,44K) lp_s
//            [44K+..] sidx[64] ints, wscr[4] floats
__global__ __launch_bounds__(256, 2) void vq_main(
    const float* __restrict__ x, const float* __restrict__ mus,
    const ushort* __restrict__ wmu, const float* __restrict__ Aarr,
    const float* __restrict__ c0arr, const float* __restrict__ lparr,
    float* __restrict__ out, float* __restrict__ partial)
{
    __shared__ __align__(16) unsigned char arena[45056 + 512];

    const int tid = threadIdx.x;
    const int w   = tid >> 6;      // wave 0..3
    const int l   = tid & 63;      // lane
    const int g   = l >> 4;        // k-group 0..3 within wave
    const int bx  = blockIdx.x;    // 0..63 pixel tile
    const int m   = blockIdx.y;    // 0..7 codebook
    const int bimg = bx >> 4;
    const int hw0  = (bx & 15) * 64;
    const size_t xbase = (size_t)bimg * (M_CB * D_CB * HW) + (size_t)m * D_CB * HW + hw0;

    float* As  = (float*)(arena + 32768);
    float* c0s = (float*)(arena + 36864);
    float* lps = (float*)(arena + 40960);
    int*   sidx = (int*)(arena + 45056);
    float* wscr = (float*)(arena + 45056 + 256);

    // ---- stage per-k consts (12 KB, once) + x tile (32 KB fp32) via global_load_lds ----
    {
        const float* srcs[3] = { Aarr + m * K_CB, c0arr + m * K_CB, lparr + m * K_CB };
        #pragma unroll
        for (int r = 0; r < 3; ++r)
            gl2lds16((const char*)srcs[r] + (size_t)(w * 1024 + l * 16),
                     arena + 32768 + r * 4096 + w * 1024);
        // x tile: row = w*4 + (l>>4) + 16r (d index), col16 = l&15 (4 pixels)
        const char* xb = (const char*)x + xbase * 4;
        #pragma unroll
        for (int r = 0; r < 8; ++r) {
            const int row = w * 4 + (l >> 4) + 16 * r;
            gl2lds16(xb + (size_t)row * 4096 + (l & 15) * 16,
                     arena + r * 4096 + w * 1024);
        }
    }
    __syncthreads();

    // ---- build x fragments (bf16) + x_sq, all in registers ----
    const int n = l & 15;                 // pixel within wave
    const float* xT = (const float*)arena;  // [128][64]
    float xs = 0.f;
    s16x8 xf[4];
    #pragma unroll
    for (int c = 0; c < 4; ++c) {
        #pragma unroll
        for (int j = 0; j < 8; ++j) {
            const int d = c * 32 + g * 8 + j;
            const float v = xT[d * 64 + w * 16 + n];
            xs = fmaf(v, v, xs);
            xf[c][j] = f2bf(v);
        }
    }
    xs += __shfl_xor(xs, 16, 64);
    xs += __shfl_xor(xs, 32, 64);         // full ||x||^2 for pixel n on all lanes
    __syncthreads();                       // done reading xT; arena[0,32K) now mu dbuf

    // ---- online state (per-lane, single pixel n, k-subset) ----
    float Mst = -1e30f, Sst = 0.f, Ust = 0.f, Vst = 0.f;
    int Ist = 0;

    const char* mubase = (const char*)wmu + (size_t)m * K_CB * 256;

    // stage chunk 0
    #pragma unroll
    for (int r = 0; r < 4; ++r)
        gl2lds16(mubase + r * 4096 + w * 1024 + l * 16, arena + r * 4096 + w * 1024);
    __syncthreads();

    for (int c = 0; c < 16; ++c) {
        const int buf = c & 1;
        // prefetch next chunk into other buffer
        if (c < 15) {
            const char* src = mubase + (size_t)(c + 1) * 16384;
            #pragma unroll
            for (int r = 0; r < 4; ++r)
                gl2lds16(src + r * 4096 + w * 1024 + l * 16,
                         arena + (buf ^ 1) * 16384 + r * 4096 + w * 1024);
        }
        const unsigned bb = buf * 16384;
        #pragma unroll
        for (int t = 0; t < 4; ++t) {
            f32x4 acc = {0.f, 0.f, 0.f, 0.f};
            const int row = t * 16 + n;
            const unsigned rbase = bb + row * 256;
            const unsigned sw = (unsigned)((row & 7) << 4);
            #pragma unroll
            for (int dc = 0; dc < 4; ++dc) {
                const s16x8 a = *(const s16x8*)(arena + rbase + (((unsigned)(dc * 64 + g * 16)) ^ sw));
                acc = __builtin_amdgcn_mfma_f32_16x16x32_bf16(a, xf[dc], acc, 0, 0, 0);
            }
            // epilogue: 4 logits (k = 64c + 16t + 4g + r)
            const int k0 = c * 64 + t * 16 + g * 4;
            const f32x4 A4  = *(const f32x4*)(As  + k0);
            const f32x4 C4  = *(const f32x4*)(c0s + k0);
            const f32x4 P4  = *(const f32x4*)(lps + k0);
            #pragma unroll
            for (int r = 0; r < 4; ++r) {
                const float L = fmaf(A4[r], fmaf(2.f, acc[r], -xs), C4[r]);
                const float lp = P4[r];
                const float diff = L - Mst;
                if (diff > 0.f) {
                    const float sc = __expf(-diff);
                    Ust = (Ust - diff * Sst) * sc;
                    Sst = fmaf(Sst, sc, 1.f);
                    Vst = fmaf(Vst, sc, lp);
                    Mst = L; Ist = k0 + r;
                } else {
                    const float e = __expf(diff);
                    Sst += e;
                    Ust = fmaf(e, diff, Ust);
                    Vst = fmaf(e, lp, Vst);
                }
            }
        }
        __syncthreads();   // drains prefetch (vmcnt0) + buffer handoff
    }

    // ---- merge the 4 k-subsets (lanes l, l^16, l^32, l^48) ----
    #pragma unroll
    for (int off = 16; off <= 32; off <<= 1) {
        float Mb = __shfl_xor(Mst, off, 64);
        float Sb = __shfl_xor(Sst, off, 64);
        float Ub = __shfl_xor(Ust, off, 64);
        float Vb = __shfl_xor(Vst, off, 64);
        int   Ib = __shfl_xor(Ist, off, 64);
        const bool takeB = (Mb > Mst) || (Mb == Mst && Ib < Ist);
        float Ma = Mst, Sa = Sst, Ua = Ust, Va = Vst; int Ia = Ist;
        if (takeB) {
            float tf;
            tf = Ma; Ma = Mb; Mb = tf;
            tf = Sa; Sa = Sb; Sb = tf;
            tf = Ua; Ua = Ub; Ub = tf;
            tf = Va; Va = Vb; Vb = tf;
            const int ti2 = Ia; Ia = Ib; Ib = ti2;
        }
        const float dm = Mb - Ma;      // <= 0
        const float sc = __expf(dm);
        Sst = fmaf(Sb, sc, Sa);
        Ust = fmaf(fmaf(dm, Sb, Ub), sc, Ua);
        Vst = fmaf(Vb, sc, Va);
        Mst = Ma; Ist = Ia;
    }

    float kl = (Ust - Vst) / Sst - logf(Sst);
    if (l < 16) sidx[w * 16 + n] = Ist;
    // block KL partial: sum over the wave's 16 pixels (all 4 groups hold identical kl)
    #pragma unroll
    for (int o = 8; o >= 1; o >>= 1) kl += __shfl_xor(kl, o, 64);
    if (l == 0) wscr[w] = kl;
    __syncthreads();
    if (tid == 0) partial[m * 64 + bx] = wscr[0] + wscr[1] + wscr[2] + wscr[3];

    // ---- write sample: out[xbase + dd*1024 + p] = mus[m][idx[p]][dd] ----
    {
        const int p = tid & 63, d0 = tid >> 6;
        const int kidx = sidx[p];
        const float* mrow = mus + ((size_t)m * K_CB + kidx) * D_CB;
        #pragma unroll 4
        for (int dd = d0; dd < D_CB; dd += 4)
            out[xbase + (size_t)dd * HW + p] = mrow[dd];
    }
}

// ---------------- kernel 4: reduce 512 partials -> kldesum ---------------------
__global__ __launch_bounds__(256) void vq_final(const float* __restrict__ partial,
                                                float* __restrict__ out)
{
    __shared__ float wred[4];
    const int tid = threadIdx.x;
    float v = partial[tid] + partial[tid + 256];
    #pragma unroll
    for (int o = 32; o >= 1; o >>= 1) v += __shfl_xor(v, o, 64);
    if ((tid & 63) == 0) wred[tid >> 6] = v;
    __syncthreads();
    if (tid == 0) {
        out[(size_t)NB * M_CB * D_CB * HW]     = (wred[0] + wred[1] + wred[2] + wred[3]) * 0.25f;
        out[(size_t)NB * M_CB * D_CB * HW + 1] = 0.f;
    }
}

extern "C" void kernel_launch(void* const* d_in, const int* in_sizes, int n_in,
                              void* d_out, int out_size, void* d_ws, size_t ws_size,
                              hipStream_t stream)
{
    const float* x      = (const float*)d_in[0];
    const float* mus    = (const float*)d_in[1];
    const float* scales = (const float*)d_in[2];
    const float* logpy  = (const float*)d_in[3];
    float* out = (float*)d_out;
    float* ws  = (float*)d_ws;

    float*  lse     = ws + WS_LSE;
    float*  partial = ws + WS_PART;
    float*  Aarr    = ws + WS_A;
    float*  c0arr   = ws + WS_C0;
    float*  lparr   = ws + WS_LP;
    ushort* wmu     = (ushort*)(ws + WS_MU_F);

    vq_pre    <<<8,           256, 0, stream>>>(logpy, lse);
    vq_convert<<<512,         256, 0, stream>>>(mus, scales, logpy, lse, wmu, Aarr, c0arr, lparr);
    vq_main   <<<dim3(64, 8), 256, 0, stream>>>(x, mus, wmu, Aarr, c0arr, lparr, out, partial);
    vq_final  <<<1,           256, 0, stream>>>(partial, out);
}